// Round 13
// baseline (1772.724 us; speedup 1.0000x reference)
//
#include <hip/hip_runtime.h>

#define T_LEN 2048
#define HID 64
#define EMB 128
#define NITER (T_LEN + 4)

typedef _Float16 half2_t __attribute__((ext_vector_type(2)));
typedef unsigned uint4v __attribute__((ext_vector_type(4)));

#if __has_builtin(__builtin_amdgcn_exp2f)
#define EXP2F(x) __builtin_amdgcn_exp2f(x)
#else
#define EXP2F(x) exp2f(x)
#endif
#if __has_builtin(__builtin_amdgcn_rcpf)
#define RCPF(x) __builtin_amdgcn_rcpf(x)
#else
#define RCPF(x) (1.0f / (x))
#endif

#define LOG2E 1.4426950408889634f

__device__ __forceinline__ float fdot2(unsigned a, unsigned b, float c) {
    return __builtin_amdgcn_fdot2(__builtin_bit_cast(half2_t, a),
                                  __builtin_bit_cast(half2_t, b), c, false);
}

__device__ __forceinline__ uint4v pack8(float4 a, float4 b, float s) {
    half2_t h0{(_Float16)(a.x * s), (_Float16)(a.y * s)};
    half2_t h1{(_Float16)(a.z * s), (_Float16)(a.w * s)};
    half2_t h2{(_Float16)(b.x * s), (_Float16)(b.y * s)};
    half2_t h3{(_Float16)(b.z * s), (_Float16)(b.w * s)};
    uint4v q;
    q[0] = __builtin_bit_cast(unsigned, h0);
    q[1] = __builtin_bit_cast(unsigned, h1);
    q[2] = __builtin_bit_cast(unsigned, h2);
    q[3] = __builtin_bit_cast(unsigned, h3);
    return q;
}

// 32 floats (half a row) -> 4 packed quads.
__device__ __forceinline__ void cvt4(const float* Wp, float s, uint4v* dst) {
    const float4* p = reinterpret_cast<const float4*>(Wp);
    #pragma unroll
    for (int k = 0; k < 4; ++k) dst[k] = pack8(p[2 * k], p[2 * k + 1], s);
}
// 64 floats (full row) -> 8 packed quads.
__device__ __forceinline__ void cvt8(const float* Wp, float s, uint4v* dst) {
    const float4* p = reinterpret_cast<const float4*>(Wp);
    #pragma unroll
    for (int k = 0; k < 8; ++k) dst[k] = pack8(p[2 * k], p[2 * k + 1], s);
}

// 32-MAC half-row dot: 16 fdot2, 2 chains.
__device__ __forceinline__ float dot16h(const uint4v* w, const uint4v* g, float init) {
    float e = init, o = 0.f;
    #pragma unroll
    for (int q = 0; q < 4; ++q) {
        e = fdot2(w[q][0], g[q][0], e);
        o = fdot2(w[q][1], g[q][1], o);
        e = fdot2(w[q][2], g[q][2], e);
        o = fdot2(w[q][3], g[q][3], o);
    }
    return e + o;
}
// 64-MAC full-row dot: w[0..3] vs glo, w[4..7] vs ghi; 4 chains.
__device__ __forceinline__ float dot32f(const uint4v* w, const uint4v* glo,
                                        const uint4v* ghi, float init) {
    float a0 = init, a1 = 0.f, a2 = 0.f, a3 = 0.f;
    #pragma unroll
    for (int q = 0; q < 4; ++q) {
        a0 = fdot2(w[q][0], glo[q][0], a0);
        a1 = fdot2(w[q][1], glo[q][1], a1);
        a2 = fdot2(w[q][2], glo[q][2], a2);
        a3 = fdot2(w[q][3], glo[q][3], a3);
    }
    #pragma unroll
    for (int q = 0; q < 4; ++q) {
        a0 = fdot2(w[4 + q][0], ghi[q][0], a0);
        a1 = fdot2(w[4 + q][1], ghi[q][1], a1);
        a2 = fdot2(w[4 + q][2], ghi[q][2], a2);
        a3 = fdot2(w[4 + q][3], ghi[q][3], a3);
    }
    return (a0 + a1) + (a2 + a3);
}

// ROUND 13 = ROUND 12 with the phase-B role-dispatch bug fixed: the guard
// `wv >= 4` also admitted wv==7 (P2), which executed the l>=2 branch with
// UNINITIALIZED w[16..23] and clobbered p2buf[wr][1] (H2's wih2_f partial)
// -> NaN into C2's forget gate. Now `wv >= 4 && wv < 7`.
//
// Structure (R12): 2-phase K-split, 512 thr = 8 waves (2/SIMD):
//   C_l (wv 0,1,2): whh_l k[0:32) 4 rows (64 fdot2) + gate init; phase B:
//                   +partial, act, cell, ring write. Cell state lane-local.
//   H_l (wv 4,5,6): whh_l k[32:64) -> part4[l] (phase A); ONE slack wih row
//                   in phase B (H0:wih1_i/h0, H1:wih2_i/h1, H2:wih2_f/h1).
//   P1 (wv 3): wih1 f,g,o (h0).  P2 (wv 7): wih2 g,o (h1).   [1-step slack]
// Per-SIMD fdot2 = 160 on all four SIMDs; per-wave max 96 -> R11's 576-cyc
// barrier skew collapses. Two barriers/iter. Weights <=96 VGPRs/wave (R11's
// spill gone); waves_per_eu(2,2) pins the 256-reg budget. exp2-prescaled
// f16 weights, f32 state.
__global__ __launch_bounds__(512, 2)
__attribute__((amdgpu_waves_per_eu(2, 2)))
void lstm3_fused(
    const float* __restrict__ x,
    const float* __restrict__ Wih0, const float* __restrict__ Whh0,
    const float* __restrict__ bih0, const float* __restrict__ bhh0,
    const float* __restrict__ Wih1, const float* __restrict__ Whh1,
    const float* __restrict__ bih1, const float* __restrict__ bhh1,
    const float* __restrict__ Wih2, const float* __restrict__ Whh2,
    const float* __restrict__ bih2, const float* __restrict__ bhh2,
    const float* __restrict__ fcW,  const float* __restrict__ fcb,
    float* __restrict__ out)
{
    const int b   = blockIdx.x;
    const int tid = threadIdx.x;
    const int wv  = tid >> 6;          // 0..7 (wave-uniform role)
    const int L   = tid & 63;          // owned h-index / row-lane

    __shared__ __align__(16) _Float16 ring[3][2][HID];   // h ring per layer
    __shared__ float p1buf[2][4][HID], p2buf[2][4][HID]; // slack ih partials
    __shared__ __align__(16) float4 part4[3][HID];       // whh k-hi partials
    __shared__ __align__(16) float xs[NITER];            // x + zero pad

    // Stage x[b,0,:] (512 float4 by 512 threads) + pad + zero rings.
    {
        const float4* xg4 = reinterpret_cast<const float4*>(x + b * T_LEN);
        float4* xs4 = reinterpret_cast<float4*>(xs);
        xs4[tid] = xg4[tid];
        if (tid == 0) xs4[512] = make_float4(0.f, 0.f, 0.f, 0.f);
    }
    if (tid < HID) {
        ring[0][0][tid] = (_Float16)0.f; ring[0][1][tid] = (_Float16)0.f;
        ring[1][0][tid] = (_Float16)0.f; ring[1][1][tid] = (_Float16)0.f;
        ring[2][0][tid] = (_Float16)0.f; ring[2][1][tid] = (_Float16)0.f;
    }

    const float scl[4] = {-LOG2E, -LOG2E, -2.f * LOG2E, -LOG2E};  // i,f,g,o

    uint4v w[24];                      // role-dependent weights (<=96 VGPRs)
    float bias4[4] = {0.f, 0.f, 0.f, 0.f};
    float wx4[4]   = {0.f, 0.f, 0.f, 0.f};

    if (wv < 3) {                      // C_l: whh_l k-lo, 4 rows
        const int l = wv;
        const float* Wh = (l == 0) ? Whh0 : (l == 1) ? Whh1 : Whh2;
        const float* bi = (l == 0) ? bih0 : (l == 1) ? bih1 : bih2;
        const float* bh = (l == 0) ? bhh0 : (l == 1) ? bhh1 : bhh2;
        #pragma unroll
        for (int c = 0; c < 4; ++c) {
            cvt4(Wh + (c * 64 + L) * 64, scl[c], &w[4 * c]);
            bias4[c] = (bi[c * 64 + L] + bh[c * 64 + L]) * scl[c];
        }
        if (l == 0) {
            #pragma unroll
            for (int c = 0; c < 4; ++c) wx4[c] = Wih0[c * 64 + L] * scl[c];
        }
    } else if (wv == 3) {              // P1: wih1 rows f,g,o
        cvt8(Wih1 + ( 64 + L) * 64, scl[1], &w[0]);
        cvt8(Wih1 + (128 + L) * 64, scl[2], &w[8]);
        cvt8(Wih1 + (192 + L) * 64, scl[3], &w[16]);
    } else if (wv == 7) {              // P2: wih2 rows g,o
        cvt8(Wih2 + (128 + L) * 64, scl[2], &w[0]);
        cvt8(Wih2 + (192 + L) * 64, scl[3], &w[8]);
    } else {                           // H_l: whh_l k-hi, 4 rows + 1 wih row
        const int l = wv - 4;
        const float* Wh = (l == 0) ? Whh0 : (l == 1) ? Whh1 : Whh2;
        #pragma unroll
        for (int c = 0; c < 4; ++c)
            cvt4(Wh + (c * 64 + L) * 64 + 32, scl[c], &w[4 * c]);
        if (l == 0)      cvt8(Wih1 + L * 64,        scl[0], &w[16]); // wih1_i
        else if (l == 1) cvt8(Wih2 + L * 64,        scl[0], &w[16]); // wih2_i
        else             cvt8(Wih2 + (64 + L) * 64, scl[1], &w[16]); // wih2_f
    }

    float cst = 0.f;                   // cell state (C waves, lane-local)
    __syncthreads();

    for (int s = 0; s < NITER; ++s) {
        const int rd = (s + 1) & 1;    // slot written at iter s-1
        const int wr = s & 1;
        uint4v g[8];
        float d0 = 0.f, d1 = 0.f, d2 = 0.f, d3 = 0.f;

        // ---------------- Phase A ----------------
        if (wv < 3) {
            const int l = wv;
            if (l == 0) {
                float xv = xs[s];
                d0 = fmaf(wx4[0], xv, bias4[0]); d1 = fmaf(wx4[1], xv, bias4[1]);
                d2 = fmaf(wx4[2], xv, bias4[2]); d3 = fmaf(wx4[3], xv, bias4[3]);
            } else {
                const float* pb = (l == 1) ? &p1buf[rd][0][L] : &p2buf[rd][0][L];
                d0 = bias4[0] + pb[0];       d1 = bias4[1] + pb[64];
                d2 = bias4[2] + pb[128];     d3 = bias4[3] + pb[192];
            }
            const uint4v* q = reinterpret_cast<const uint4v*>(&ring[l][rd][0]);
            g[0] = q[0]; g[1] = q[1]; g[2] = q[2]; g[3] = q[3];   // k-lo
            d0 = dot16h(&w[0],  g, d0);
            d1 = dot16h(&w[4],  g, d1);
            d2 = dot16h(&w[8],  g, d2);
            d3 = dot16h(&w[12], g, d3);
        } else if (wv == 3) {
            const uint4v* q = reinterpret_cast<const uint4v*>(&ring[0][rd][0]);
            #pragma unroll
            for (int k = 0; k < 8; ++k) g[k] = q[k];              // h0 full
            p1buf[wr][1][L] = dot32f(&w[0],  &g[0], &g[4], 0.f);
            p1buf[wr][2][L] = dot32f(&w[8],  &g[0], &g[4], 0.f);
            p1buf[wr][3][L] = dot32f(&w[16], &g[0], &g[4], 0.f);
        } else if (wv == 7) {
            const uint4v* q = reinterpret_cast<const uint4v*>(&ring[1][rd][0]);
            #pragma unroll
            for (int k = 0; k < 8; ++k) g[k] = q[k];              // h1 full
            p2buf[wr][2][L] = dot32f(&w[0], &g[0], &g[4], 0.f);
            p2buf[wr][3][L] = dot32f(&w[8], &g[0], &g[4], 0.f);
        } else {
            const int l = wv - 4;
            const uint4v* q = reinterpret_cast<const uint4v*>(&ring[l][rd][0]) + 4;
            g[0] = q[0]; g[1] = q[1]; g[2] = q[2]; g[3] = q[3];   // k-hi
            float e0 = dot16h(&w[0],  g, 0.f);
            float e1 = dot16h(&w[4],  g, 0.f);
            float e2 = dot16h(&w[8],  g, 0.f);
            float e3 = dot16h(&w[12], g, 0.f);
            part4[l][L] = make_float4(e0, e1, e2, e3);            // 1x b128
        }

        __syncthreads();   // barrier B: whh k-hi partials visible

        // ---------------- Phase B ----------------
        if (wv < 3) {
            const int l = wv;
            float4 pt = part4[l][L];                              // 1x b128
            d0 += pt.x; d1 += pt.y; d2 += pt.z; d3 += pt.w;
            float ai = RCPF(1.f + EXP2F(d0));
            float af = RCPF(1.f + EXP2F(d1));
            float ag = fmaf(2.f, RCPF(1.f + EXP2F(d2)), -1.f);
            float ao = RCPF(1.f + EXP2F(d3));
            if ((unsigned)(s - 2 * l) < (unsigned)T_LEN) {
                cst = fmaf(af, cst, ai * ag);
                float tc = fmaf(2.f, RCPF(1.f + EXP2F(-2.f * LOG2E * cst)), -1.f);
                ring[l][wr][L] = (_Float16)(ao * tc);
            }
        } else if (wv >= 4 && wv < 7) {   // H waves ONLY (R12 bug: wv==7 fell in here)
            const int l = wv - 4;
            if (l < 2) {
                // own-ring k-lo into g[4..7]; k-hi already in g[0..3]
                const uint4v* q = reinterpret_cast<const uint4v*>(&ring[l][rd][0]);
                g[4] = q[0]; g[5] = q[1]; g[6] = q[2]; g[7] = q[3];
                float pv = dot32f(&w[16], &g[4], &g[0], 0.f);
                if (l == 0) p1buf[wr][0][L] = pv;   // wih1_i
                else        p2buf[wr][0][L] = pv;   // wih2_i
            } else {
                const uint4v* q = reinterpret_cast<const uint4v*>(&ring[1][rd][0]);
                #pragma unroll
                for (int k = 0; k < 8; ++k) g[k] = q[k];          // h1 full
                p2buf[wr][1][L] = dot32f(&w[16], &g[0], &g[4], 0.f);  // wih2_f
            }
        }

        __syncthreads();   // end barrier: rings + slack p-bufs visible
    }

    // Final FC (f32): h2[T-1] written at s=2051 (odd) -> ring slot 1.
    if (tid < EMB) {
        float acc = fcb[tid];
        const _Float16* hf = &ring[2][1][0];
        const float4* W4 = reinterpret_cast<const float4*>(fcW + tid * HID);
        #pragma unroll
        for (int k = 0; k < 16; ++k) {
            float4 wv4 = W4[k];
            acc = fmaf(wv4.x, (float)hf[4 * k + 0], acc);
            acc = fmaf(wv4.y, (float)hf[4 * k + 1], acc);
            acc = fmaf(wv4.z, (float)hf[4 * k + 2], acc);
            acc = fmaf(wv4.w, (float)hf[4 * k + 3], acc);
        }
        out[b * EMB + tid] = acc;
    }
}

extern "C" void kernel_launch(void* const* d_in, const int* in_sizes, int n_in,
                              void* d_out, int out_size, void* d_ws, size_t ws_size,
                              hipStream_t stream) {
    const float* x    = (const float*)d_in[0];
    const float* Wih0 = (const float*)d_in[1];
    const float* Whh0 = (const float*)d_in[2];
    const float* bih0 = (const float*)d_in[3];
    const float* bhh0 = (const float*)d_in[4];
    const float* Wih1 = (const float*)d_in[5];
    const float* Whh1 = (const float*)d_in[6];
    const float* bih1 = (const float*)d_in[7];
    const float* bhh1 = (const float*)d_in[8];
    const float* Wih2 = (const float*)d_in[9];
    const float* Whh2 = (const float*)d_in[10];
    const float* bih2 = (const float*)d_in[11];
    const float* bhh2 = (const float*)d_in[12];
    const float* fcW  = (const float*)d_in[13];
    const float* fcb  = (const float*)d_in[14];
    float* out = (float*)d_out;

    lstm3_fused<<<dim3(256), dim3(512), 0, stream>>>(
        x, Wih0, Whh0, bih0, bhh0,
        Wih1, Whh1, bih1, bhh1,
        Wih2, Whh2, bih2, bhh2,
        fcW, fcb, out);
}

// Round 14
// 1133.229 us; speedup vs baseline: 1.5643x; 1.5643x over previous
//
#include <hip/hip_runtime.h>

#define T_LEN 2048
#define HID 64
#define EMB 128
#define WD 8                 // steps per window (barrier period)
#define NWIN (T_LEN / WD)    // 256
#define NPH (NWIN + 4)       // +4 windows of pipeline lag (C2)

typedef _Float16 half2_t __attribute__((ext_vector_type(2)));
typedef unsigned uint4v __attribute__((ext_vector_type(4)));

#if __has_builtin(__builtin_amdgcn_exp2f)
#define EXP2F(x) __builtin_amdgcn_exp2f(x)
#else
#define EXP2F(x) exp2f(x)
#endif
#if __has_builtin(__builtin_amdgcn_rcpf)
#define RCPF(x) __builtin_amdgcn_rcpf(x)
#else
#define RCPF(x) (1.0f / (x))
#endif

#define LOG2E 1.4426950408889634f

__device__ __forceinline__ float fdot2(unsigned a, unsigned b, float c) {
    return __builtin_amdgcn_fdot2(__builtin_bit_cast(half2_t, a),
                                  __builtin_bit_cast(half2_t, b), c, false);
}

// Full-row 64-MAC dot: 8 weight quads vs 8 gathered-h quads, 4 chains.
__device__ __forceinline__ float dotrow(const uint4v* w, const uint4v* g, float init) {
    float a0 = init, a1 = 0.f, a2 = 0.f, a3 = 0.f;
    #pragma unroll
    for (int q = 0; q < 8; ++q) {
        a0 = fdot2(w[q][0], g[q][0], a0);
        a1 = fdot2(w[q][1], g[q][1], a1);
        a2 = fdot2(w[q][2], g[q][2], a2);
        a3 = fdot2(w[q][3], g[q][3], a3);
    }
    return (a0 + a1) + (a2 + a3);
}

__device__ __forceinline__ uint4v pack8(float4 a, float4 b, float s) {
    half2_t h0{(_Float16)(a.x * s), (_Float16)(a.y * s)};
    half2_t h1{(_Float16)(a.z * s), (_Float16)(a.w * s)};
    half2_t h2{(_Float16)(b.x * s), (_Float16)(b.y * s)};
    half2_t h3{(_Float16)(b.z * s), (_Float16)(b.w * s)};
    uint4v q;
    q[0] = __builtin_bit_cast(unsigned, h0);
    q[1] = __builtin_bit_cast(unsigned, h1);
    q[2] = __builtin_bit_cast(unsigned, h2);
    q[3] = __builtin_bit_cast(unsigned, h3);
    return q;
}

// One 64-float weight row -> 8 packed quads, exp2-space prescaled.
__device__ __forceinline__ void cvt8(const float* __restrict__ Wp, float s, uint4v* dst) {
    const float4* p = reinterpret_cast<const float4*>(Wp);
    #pragma unroll
    for (int k = 0; k < 8; ++k) dst[k] = pack8(p[2 * k], p[2 * k + 1], s);
}

// ROUND 14: windowed layer-lag pipeline — barrier every WD=8 steps (R13
// proved per-step barriers cost ~300-550 cyc each; R11's single barrier was
// ~40% of the iteration). Layer l lags layer l-1 by 2 windows:
//   phase ph: C0 computes h0 window ph; P1 waves compute p1 = Wih1.h0 for
//   window ph-1; C1 computes h1 window ph-2 (p1 ready); P2 waves p2 for h1
//   window ph-3; C2 computes h2 window ph-4. One barrier per phase.
// Within a window each C wave runs its scalar recurrence PRIVATELY: the
// self-ring write->read is same-wave (lgkmcnt-ordered, no barrier).
// Waves (512 thr): wv0/1/2 = C0/C1/C2 (4 whh rows in VGPRs = 128 fdot2/step,
// in-lane gates, scalar cell — R10 model); wv4=wih1_{i,f}, wv5=wih1_{g,o},
// wv6=wih2_{i,f}, wv3=wih2_{g,o} (2 full-K rows = 64 fdot2/step); wv7 spare.
// h rings: 16 slots (2 windows, parity halves); p-bufs double-buffered by
// window parity; all LDS lane-linear (<=2-way, free). x staged once.
// waves_per_eu(2,2): VGPR cap 256 >= ~180 the C waves need -> no AGPR
// parking tax (R13 showed (2,2) allocates what's needed).
__global__ __launch_bounds__(512)
__attribute__((amdgpu_waves_per_eu(2, 2)))
void lstm3_fused(
    const float* __restrict__ x,
    const float* __restrict__ Wih0, const float* __restrict__ Whh0,
    const float* __restrict__ bih0, const float* __restrict__ bhh0,
    const float* __restrict__ Wih1, const float* __restrict__ Whh1,
    const float* __restrict__ bih1, const float* __restrict__ bhh1,
    const float* __restrict__ Wih2, const float* __restrict__ Whh2,
    const float* __restrict__ bih2, const float* __restrict__ bhh2,
    const float* __restrict__ fcW,  const float* __restrict__ fcb,
    float* __restrict__ out)
{
    const int b   = blockIdx.x;
    const int tid = threadIdx.x;
    const int wv  = tid >> 6;          // 0..7 (wave-uniform role)
    const int L   = tid & 63;          // owned h-index / row-lane

    __shared__ __align__(16) _Float16 h0ring[16][HID];   // 2 windows of h0
    __shared__ __align__(16) _Float16 h1ring[16][HID];   // 2 windows of h1
    __shared__ __align__(16) _Float16 h2ring[2][HID];    // h2 self-ring only
    __shared__ float p1buf[2][WD][4][HID];               // wih1 partials
    __shared__ float p2buf[2][WD][4][HID];               // wih2 partials
    __shared__ __align__(16) float xs[T_LEN];

    // Stage x[b,0,:] (512 float4 by 512 threads); zero the rings.
    {
        const float4* xg4 = reinterpret_cast<const float4*>(x + b * T_LEN);
        reinterpret_cast<float4*>(xs)[tid] = xg4[tid];
        reinterpret_cast<unsigned*>(h0ring)[tid] = 0u;   // 512 dwords
        reinterpret_cast<unsigned*>(h1ring)[tid] = 0u;
        if (tid < 64) reinterpret_cast<unsigned*>(h2ring)[tid] = 0u;
    }

    const float sI = -LOG2E, sF = -LOG2E, sG = -2.f * LOG2E, sO = -LOG2E;
    const float scl[4] = {sI, sF, sG, sO};

    uint4v w[4][8];                    // C: 4 whh rows (128 VGPR); P: 2 rows
    float bias4[4] = {0.f, 0.f, 0.f, 0.f};
    float wx4[4]   = {0.f, 0.f, 0.f, 0.f};

    if (wv < 3) {                      // C_l: whh_l all 4 gate rows
        const float* Wh = (wv == 0) ? Whh0 : (wv == 1) ? Whh1 : Whh2;
        const float* bi = (wv == 0) ? bih0 : (wv == 1) ? bih1 : bih2;
        const float* bh = (wv == 0) ? bhh0 : (wv == 1) ? bhh1 : bhh2;
        #pragma unroll
        for (int c = 0; c < 4; ++c) {
            cvt8(Wh + (c * 64 + L) * 64, scl[c], w[c]);
            bias4[c] = (bi[c * 64 + L] + bh[c * 64 + L]) * scl[c];
        }
        if (wv == 0) {
            #pragma unroll
            for (int c = 0; c < 4; ++c) wx4[c] = Wih0[c * 64 + L] * scl[c];
        }
    } else if (wv == 4) {              // P1 rows i,f
        cvt8(Wih1 + (  0 + L) * 64, sI, w[0]);
        cvt8(Wih1 + ( 64 + L) * 64, sF, w[1]);
    } else if (wv == 5) {              // P1 rows g,o
        cvt8(Wih1 + (128 + L) * 64, sG, w[0]);
        cvt8(Wih1 + (192 + L) * 64, sO, w[1]);
    } else if (wv == 6) {              // P2 rows i,f
        cvt8(Wih2 + (  0 + L) * 64, sI, w[0]);
        cvt8(Wih2 + ( 64 + L) * 64, sF, w[1]);
    } else if (wv == 3) {              // P2 rows g,o
        cvt8(Wih2 + (128 + L) * 64, sG, w[0]);
        cvt8(Wih2 + (192 + L) * 64, sO, w[1]);
    }                                   // wv==7: spare

    float cst = 0.f;                   // cell state (C waves, lane-local)
    __syncthreads();

    for (int ph = 0; ph < NPH; ++ph) {
        const int par = ph & 1;

        if (wv == 0) {
            if (ph < NWIN) {           // h0 window ph
                _Float16* cur = &h0ring[par * 8][0];
                const _Float16* prv = &h0ring[(par ^ 1) * 8][0];
                const int tb = ph * WD;
                #pragma unroll
                for (int j = 0; j < WD; ++j) {
                    const uint4v* hp = reinterpret_cast<const uint4v*>(
                        (j == 0) ? (prv + 7 * HID) : (cur + (j - 1) * HID));
                    uint4v g[8];
                    #pragma unroll
                    for (int k = 0; k < 8; ++k) g[k] = hp[k];
                    float xv = xs[tb + j];
                    float d0 = dotrow(w[0], g, fmaf(wx4[0], xv, bias4[0]));
                    float d1 = dotrow(w[1], g, fmaf(wx4[1], xv, bias4[1]));
                    float d2 = dotrow(w[2], g, fmaf(wx4[2], xv, bias4[2]));
                    float d3 = dotrow(w[3], g, fmaf(wx4[3], xv, bias4[3]));
                    float ai = RCPF(1.f + EXP2F(d0));
                    float af = RCPF(1.f + EXP2F(d1));
                    float ag = fmaf(2.f, RCPF(1.f + EXP2F(d2)), -1.f);
                    float ao = RCPF(1.f + EXP2F(d3));
                    cst = fmaf(af, cst, ai * ag);
                    float tc = fmaf(2.f, RCPF(1.f + EXP2F(-2.f * LOG2E * cst)), -1.f);
                    cur[j * HID + L] = (_Float16)(ao * tc);
                }
            }
        } else if (wv == 1) {
            if (ph >= 2 && ph < NWIN + 2) {    // h1 window ph-2 (p1[par] ready)
                _Float16* cur = &h1ring[par * 8][0];
                const _Float16* prv = &h1ring[(par ^ 1) * 8][0];
                const float (*pb)[4][HID] = p1buf[par];
                #pragma unroll
                for (int j = 0; j < WD; ++j) {
                    const uint4v* hp = reinterpret_cast<const uint4v*>(
                        (j == 0) ? (prv + 7 * HID) : (cur + (j - 1) * HID));
                    uint4v g[8];
                    #pragma unroll
                    for (int k = 0; k < 8; ++k) g[k] = hp[k];
                    float d0 = dotrow(w[0], g, bias4[0] + pb[j][0][L]);
                    float d1 = dotrow(w[1], g, bias4[1] + pb[j][1][L]);
                    float d2 = dotrow(w[2], g, bias4[2] + pb[j][2][L]);
                    float d3 = dotrow(w[3], g, bias4[3] + pb[j][3][L]);
                    float ai = RCPF(1.f + EXP2F(d0));
                    float af = RCPF(1.f + EXP2F(d1));
                    float ag = fmaf(2.f, RCPF(1.f + EXP2F(d2)), -1.f);
                    float ao = RCPF(1.f + EXP2F(d3));
                    cst = fmaf(af, cst, ai * ag);
                    float tc = fmaf(2.f, RCPF(1.f + EXP2F(-2.f * LOG2E * cst)), -1.f);
                    cur[j * HID + L] = (_Float16)(ao * tc);
                }
            }
        } else if (wv == 2) {
            if (ph >= 4) {                     // h2 window ph-4 (p2[par] ready)
                const float (*pb)[4][HID] = p2buf[par];
                #pragma unroll
                for (int j = 0; j < WD; ++j) {
                    // self-ring [2]: write slot j&1, read slot (j&1)^1
                    const uint4v* hp = reinterpret_cast<const uint4v*>(
                        &h2ring[(j & 1) ^ 1][0]);
                    uint4v g[8];
                    #pragma unroll
                    for (int k = 0; k < 8; ++k) g[k] = hp[k];
                    float d0 = dotrow(w[0], g, bias4[0] + pb[j][0][L]);
                    float d1 = dotrow(w[1], g, bias4[1] + pb[j][1][L]);
                    float d2 = dotrow(w[2], g, bias4[2] + pb[j][2][L]);
                    float d3 = dotrow(w[3], g, bias4[3] + pb[j][3][L]);
                    float ai = RCPF(1.f + EXP2F(d0));
                    float af = RCPF(1.f + EXP2F(d1));
                    float ag = fmaf(2.f, RCPF(1.f + EXP2F(d2)), -1.f);
                    float ao = RCPF(1.f + EXP2F(d3));
                    cst = fmaf(af, cst, ai * ag);
                    float tc = fmaf(2.f, RCPF(1.f + EXP2F(-2.f * LOG2E * cst)), -1.f);
                    h2ring[j & 1][L] = (_Float16)(ao * tc);
                }
            }
        } else if (wv == 4 || wv == 5) {
            if (ph >= 1 && ph < NWIN + 1) {    // p1 for h0 window ph-1
                const _Float16* hw = &h0ring[(par ^ 1) * 8][0];
                float (*po)[4][HID] = p1buf[par ^ 1];
                const int c0 = (wv == 4) ? 0 : 2;
                #pragma unroll
                for (int j = 0; j < WD; ++j) {
                    const uint4v* hp = reinterpret_cast<const uint4v*>(hw + j * HID);
                    uint4v g[8];
                    #pragma unroll
                    for (int k = 0; k < 8; ++k) g[k] = hp[k];
                    po[j][c0 + 0][L] = dotrow(w[0], g, 0.f);
                    po[j][c0 + 1][L] = dotrow(w[1], g, 0.f);
                }
            }
        } else if (wv == 6 || wv == 3) {
            if (ph >= 3 && ph < NWIN + 3) {    // p2 for h1 window ph-3
                const _Float16* hw = &h1ring[(par ^ 1) * 8][0];
                float (*po)[4][HID] = p2buf[par ^ 1];
                const int c0 = (wv == 6) ? 0 : 2;
                #pragma unroll
                for (int j = 0; j < WD; ++j) {
                    const uint4v* hp = reinterpret_cast<const uint4v*>(hw + j * HID);
                    uint4v g[8];
                    #pragma unroll
                    for (int k = 0; k < 8; ++k) g[k] = hp[k];
                    po[j][c0 + 0][L] = dotrow(w[0], g, 0.f);
                    po[j][c0 + 1][L] = dotrow(w[1], g, 0.f);
                }
            }
        }
        // wv == 7: spare

        __syncthreads();   // publish window: h rings + p-buffers
    }

    // Final FC (f32): h2[2047] -> slot 2047&1 = 1.
    if (tid < EMB) {
        float acc = fcb[tid];
        const _Float16* hf = &h2ring[1][0];
        const float4* W4 = reinterpret_cast<const float4*>(fcW + tid * HID);
        #pragma unroll
        for (int k = 0; k < 16; ++k) {
            float4 wv4 = W4[k];
            acc = fmaf(wv4.x, (float)hf[4 * k + 0], acc);
            acc = fmaf(wv4.y, (float)hf[4 * k + 1], acc);
            acc = fmaf(wv4.z, (float)hf[4 * k + 2], acc);
            acc = fmaf(wv4.w, (float)hf[4 * k + 3], acc);
        }
        out[b * EMB + tid] = acc;
    }
}

extern "C" void kernel_launch(void* const* d_in, const int* in_sizes, int n_in,
                              void* d_out, int out_size, void* d_ws, size_t ws_size,
                              hipStream_t stream) {
    const float* x    = (const float*)d_in[0];
    const float* Wih0 = (const float*)d_in[1];
    const float* Whh0 = (const float*)d_in[2];
    const float* bih0 = (const float*)d_in[3];
    const float* bhh0 = (const float*)d_in[4];
    const float* Wih1 = (const float*)d_in[5];
    const float* Whh1 = (const float*)d_in[6];
    const float* bih1 = (const float*)d_in[7];
    const float* bhh1 = (const float*)d_in[8];
    const float* Wih2 = (const float*)d_in[9];
    const float* Whh2 = (const float*)d_in[10];
    const float* bih2 = (const float*)d_in[11];
    const float* bhh2 = (const float*)d_in[12];
    const float* fcW  = (const float*)d_in[13];
    const float* fcb  = (const float*)d_in[14];
    float* out = (float*)d_out;

    lstm3_fused<<<dim3(256), dim3(512), 0, stream>>>(
        x, Wih0, Whh0, bih0, bhh0,
        Wih1, Whh1, bih1, bhh1,
        Wih2, Whh2, bih2, bhh2,
        fcW, fcb, out);
}

// Round 15
// 976.735 us; speedup vs baseline: 1.8149x; 1.1602x over previous
//
#include <hip/hip_runtime.h>

#define T_LEN 2048
#define HID 64
#define EMB 128
#define WD 8                 // steps per window (barrier period)
#define NWIN (T_LEN / WD)    // 256
#define NPH (NWIN + 4)       // +4 windows of pipeline lag (C2)

typedef _Float16 half2_t __attribute__((ext_vector_type(2)));
typedef unsigned uint4v __attribute__((ext_vector_type(4)));

#if __has_builtin(__builtin_amdgcn_exp2f)
#define EXP2F(x) __builtin_amdgcn_exp2f(x)
#else
#define EXP2F(x) exp2f(x)
#endif
#if __has_builtin(__builtin_amdgcn_rcpf)
#define RCPF(x) __builtin_amdgcn_rcpf(x)
#else
#define RCPF(x) (1.0f / (x))
#endif

#define LOG2E 1.4426950408889634f

__device__ __forceinline__ float fdot2(unsigned a, unsigned b, float c) {
    return __builtin_amdgcn_fdot2(__builtin_bit_cast(half2_t, a),
                                  __builtin_bit_cast(half2_t, b), c, false);
}

// Full-row 64-MAC dot: 8 weight quads vs 8 gathered-h quads, 4 chains.
__device__ __forceinline__ float dotrow(const uint4v* w, const uint4v* g, float init) {
    float a0 = init, a1 = 0.f, a2 = 0.f, a3 = 0.f;
    #pragma unroll
    for (int q = 0; q < 8; ++q) {
        a0 = fdot2(w[q][0], g[q][0], a0);
        a1 = fdot2(w[q][1], g[q][1], a1);
        a2 = fdot2(w[q][2], g[q][2], a2);
        a3 = fdot2(w[q][3], g[q][3], a3);
    }
    return (a0 + a1) + (a2 + a3);
}

__device__ __forceinline__ uint4v pack8(float4 a, float4 b, float s) {
    half2_t h0{(_Float16)(a.x * s), (_Float16)(a.y * s)};
    half2_t h1{(_Float16)(a.z * s), (_Float16)(a.w * s)};
    half2_t h2{(_Float16)(b.x * s), (_Float16)(b.y * s)};
    half2_t h3{(_Float16)(b.z * s), (_Float16)(b.w * s)};
    uint4v q;
    q[0] = __builtin_bit_cast(unsigned, h0);
    q[1] = __builtin_bit_cast(unsigned, h1);
    q[2] = __builtin_bit_cast(unsigned, h2);
    q[3] = __builtin_bit_cast(unsigned, h3);
    return q;
}

// One 64-float weight row -> 8 packed quads, exp2-space prescaled.
__device__ __forceinline__ void cvt8(const float* __restrict__ Wp, float s, uint4v* dst) {
    const float4* p = reinterpret_cast<const float4*>(Wp);
    #pragma unroll
    for (int k = 0; k < 8; ++k) dst[k] = pack8(p[2 * k], p[2 * k + 1], s);
}

// ROUND 15 = ROUND 14 (windowed layer-lag, barrier every WD=8 steps) with the
// producer rows REBALANCED across SIMDs. R14 analysis: busy ~ 4 cyc/fdot2
// (v_dot2_f32_f16 = 32 MAC/cyc/SIMD); round-robin wave->SIMD put C+2P-rows
// on SIMD0-2 (6144 dot-cyc/phase) and only 2 P rows on SIMD3 (2048, wv7
// spare). New assignment equalizes ALL FOUR SIMDs at 5120 dot-cyc/phase:
//   wv0/1/2 = C0/C1/C2 (4 whh rows, in-lane gates, scalar cell)  [S0/S1/S2]
//   wv4 = wih1_i, wv5 = wih1_f, wv6 = wih1_g (1 row each)        [S0/S1/S2]
//   wv3 = wih1_o + wih2_i (2 rows)                               [S3]
//   wv7 = wih2_{f,g,o}    (3 rows)                               [S3]
// Schedule (R14): phase ph: C0 h0-window ph | p1 for window ph-1 | C1 h1
// window ph-2 | p2 for window ph-3 | C2 h2 window ph-4. One barrier/phase.
// Within a window C waves recurse privately (same-wave lgkmcnt ordering).
__global__ __launch_bounds__(512)
__attribute__((amdgpu_waves_per_eu(2, 2)))
void lstm3_fused(
    const float* __restrict__ x,
    const float* __restrict__ Wih0, const float* __restrict__ Whh0,
    const float* __restrict__ bih0, const float* __restrict__ bhh0,
    const float* __restrict__ Wih1, const float* __restrict__ Whh1,
    const float* __restrict__ bih1, const float* __restrict__ bhh1,
    const float* __restrict__ Wih2, const float* __restrict__ Whh2,
    const float* __restrict__ bih2, const float* __restrict__ bhh2,
    const float* __restrict__ fcW,  const float* __restrict__ fcb,
    float* __restrict__ out)
{
    const int b   = blockIdx.x;
    const int tid = threadIdx.x;
    const int wv  = tid >> 6;          // 0..7 (wave-uniform role)
    const int L   = tid & 63;          // owned h-index / row-lane

    __shared__ __align__(16) _Float16 h0ring[16][HID];   // 2 windows of h0
    __shared__ __align__(16) _Float16 h1ring[16][HID];   // 2 windows of h1
    __shared__ __align__(16) _Float16 h2ring[2][HID];    // h2 self-ring only
    __shared__ float p1buf[2][WD][4][HID];               // wih1 partials
    __shared__ float p2buf[2][WD][4][HID];               // wih2 partials
    __shared__ __align__(16) float xs[T_LEN];

    // Stage x[b,0,:] (512 float4 by 512 threads); zero the rings.
    {
        const float4* xg4 = reinterpret_cast<const float4*>(x + b * T_LEN);
        reinterpret_cast<float4*>(xs)[tid] = xg4[tid];
        reinterpret_cast<unsigned*>(h0ring)[tid] = 0u;   // 512 dwords
        reinterpret_cast<unsigned*>(h1ring)[tid] = 0u;
        if (tid < 64) reinterpret_cast<unsigned*>(h2ring)[tid] = 0u;
    }

    const float sI = -LOG2E, sF = -LOG2E, sG = -2.f * LOG2E, sO = -LOG2E;
    const float scl[4] = {sI, sF, sG, sO};

    uint4v w[4][8];                    // C: 4 whh rows; wv3: 2; wv7: 3
    float bias4[4] = {0.f, 0.f, 0.f, 0.f};
    float wx4[4]   = {0.f, 0.f, 0.f, 0.f};

    if (wv < 3) {                      // C_l: whh_l all 4 gate rows
        const float* Wh = (wv == 0) ? Whh0 : (wv == 1) ? Whh1 : Whh2;
        const float* bi = (wv == 0) ? bih0 : (wv == 1) ? bih1 : bih2;
        const float* bh = (wv == 0) ? bhh0 : (wv == 1) ? bhh1 : bhh2;
        #pragma unroll
        for (int c = 0; c < 4; ++c) {
            cvt8(Wh + (c * 64 + L) * 64, scl[c], w[c]);
            bias4[c] = (bi[c * 64 + L] + bh[c * 64 + L]) * scl[c];
        }
        if (wv == 0) {
            #pragma unroll
            for (int c = 0; c < 4; ++c) wx4[c] = Wih0[c * 64 + L] * scl[c];
        }
    } else if (wv == 4) {              // P: wih1_i
        cvt8(Wih1 + (  0 + L) * 64, sI, w[0]);
    } else if (wv == 5) {              // P: wih1_f
        cvt8(Wih1 + ( 64 + L) * 64, sF, w[0]);
    } else if (wv == 6) {              // P: wih1_g
        cvt8(Wih1 + (128 + L) * 64, sG, w[0]);
    } else if (wv == 3) {              // P: wih1_o + wih2_i
        cvt8(Wih1 + (192 + L) * 64, sO, w[0]);
        cvt8(Wih2 + (  0 + L) * 64, sI, w[1]);
    } else {                           // wv == 7: wih2_{f,g,o}
        cvt8(Wih2 + ( 64 + L) * 64, sF, w[0]);
        cvt8(Wih2 + (128 + L) * 64, sG, w[1]);
        cvt8(Wih2 + (192 + L) * 64, sO, w[2]);
    }

    float cst = 0.f;                   // cell state (C waves, lane-local)
    __syncthreads();

    for (int ph = 0; ph < NPH; ++ph) {
        const int par = ph & 1;

        if (wv == 0) {
            if (ph < NWIN) {           // h0 window ph
                _Float16* cur = &h0ring[par * 8][0];
                const _Float16* prv = &h0ring[(par ^ 1) * 8][0];
                const int tb = ph * WD;
                #pragma unroll
                for (int j = 0; j < WD; ++j) {
                    const uint4v* hp = reinterpret_cast<const uint4v*>(
                        (j == 0) ? (prv + 7 * HID) : (cur + (j - 1) * HID));
                    uint4v g[8];
                    #pragma unroll
                    for (int k = 0; k < 8; ++k) g[k] = hp[k];
                    float xv = xs[tb + j];
                    float d0 = dotrow(w[0], g, fmaf(wx4[0], xv, bias4[0]));
                    float d1 = dotrow(w[1], g, fmaf(wx4[1], xv, bias4[1]));
                    float d2 = dotrow(w[2], g, fmaf(wx4[2], xv, bias4[2]));
                    float d3 = dotrow(w[3], g, fmaf(wx4[3], xv, bias4[3]));
                    float ai = RCPF(1.f + EXP2F(d0));
                    float af = RCPF(1.f + EXP2F(d1));
                    float ag = fmaf(2.f, RCPF(1.f + EXP2F(d2)), -1.f);
                    float ao = RCPF(1.f + EXP2F(d3));
                    cst = fmaf(af, cst, ai * ag);
                    float tc = fmaf(2.f, RCPF(1.f + EXP2F(-2.f * LOG2E * cst)), -1.f);
                    cur[j * HID + L] = (_Float16)(ao * tc);
                }
            }
        } else if (wv == 1) {
            if (ph >= 2 && ph < NWIN + 2) {    // h1 window ph-2 (p1[par] ready)
                _Float16* cur = &h1ring[par * 8][0];
                const _Float16* prv = &h1ring[(par ^ 1) * 8][0];
                const float (*pb)[4][HID] = p1buf[par];
                #pragma unroll
                for (int j = 0; j < WD; ++j) {
                    const uint4v* hp = reinterpret_cast<const uint4v*>(
                        (j == 0) ? (prv + 7 * HID) : (cur + (j - 1) * HID));
                    uint4v g[8];
                    #pragma unroll
                    for (int k = 0; k < 8; ++k) g[k] = hp[k];
                    float d0 = dotrow(w[0], g, bias4[0] + pb[j][0][L]);
                    float d1 = dotrow(w[1], g, bias4[1] + pb[j][1][L]);
                    float d2 = dotrow(w[2], g, bias4[2] + pb[j][2][L]);
                    float d3 = dotrow(w[3], g, bias4[3] + pb[j][3][L]);
                    float ai = RCPF(1.f + EXP2F(d0));
                    float af = RCPF(1.f + EXP2F(d1));
                    float ag = fmaf(2.f, RCPF(1.f + EXP2F(d2)), -1.f);
                    float ao = RCPF(1.f + EXP2F(d3));
                    cst = fmaf(af, cst, ai * ag);
                    float tc = fmaf(2.f, RCPF(1.f + EXP2F(-2.f * LOG2E * cst)), -1.f);
                    cur[j * HID + L] = (_Float16)(ao * tc);
                }
            }
        } else if (wv == 2) {
            if (ph >= 4) {                     // h2 window ph-4 (p2[par] ready)
                const float (*pb)[4][HID] = p2buf[par];
                #pragma unroll
                for (int j = 0; j < WD; ++j) {
                    const uint4v* hp = reinterpret_cast<const uint4v*>(
                        &h2ring[(j & 1) ^ 1][0]);
                    uint4v g[8];
                    #pragma unroll
                    for (int k = 0; k < 8; ++k) g[k] = hp[k];
                    float d0 = dotrow(w[0], g, bias4[0] + pb[j][0][L]);
                    float d1 = dotrow(w[1], g, bias4[1] + pb[j][1][L]);
                    float d2 = dotrow(w[2], g, bias4[2] + pb[j][2][L]);
                    float d3 = dotrow(w[3], g, bias4[3] + pb[j][3][L]);
                    float ai = RCPF(1.f + EXP2F(d0));
                    float af = RCPF(1.f + EXP2F(d1));
                    float ag = fmaf(2.f, RCPF(1.f + EXP2F(d2)), -1.f);
                    float ao = RCPF(1.f + EXP2F(d3));
                    cst = fmaf(af, cst, ai * ag);
                    float tc = fmaf(2.f, RCPF(1.f + EXP2F(-2.f * LOG2E * cst)), -1.f);
                    h2ring[j & 1][L] = (_Float16)(ao * tc);
                }
            }
        } else {
            // Producer roles. p1 active: ph in [1, NWIN]; p2: ph in [3, NWIN+2].
            const bool p1act = (ph >= 1 && ph < NWIN + 1);
            const bool p2act = (ph >= 3 && ph < NWIN + 3);
            if (wv == 4 || wv == 5 || wv == 6) {
                if (p1act) {                   // one wih1 row vs h0 window ph-1
                    const _Float16* hw = &h0ring[(par ^ 1) * 8][0];
                    float (*po)[4][HID] = p1buf[par ^ 1];
                    const int c0 = wv - 4;     // 4->i(0), 5->f(1), 6->g(2)
                    #pragma unroll
                    for (int j = 0; j < WD; ++j) {
                        const uint4v* hp = reinterpret_cast<const uint4v*>(hw + j * HID);
                        uint4v g[8];
                        #pragma unroll
                        for (int k = 0; k < 8; ++k) g[k] = hp[k];
                        po[j][c0][L] = dotrow(w[0], g, 0.f);
                    }
                }
            } else if (wv == 3) {
                if (p1act) {                   // wih1_o vs h0 window ph-1
                    const _Float16* hw = &h0ring[(par ^ 1) * 8][0];
                    float (*po)[4][HID] = p1buf[par ^ 1];
                    #pragma unroll
                    for (int j = 0; j < WD; ++j) {
                        const uint4v* hp = reinterpret_cast<const uint4v*>(hw + j * HID);
                        uint4v g[8];
                        #pragma unroll
                        for (int k = 0; k < 8; ++k) g[k] = hp[k];
                        po[j][3][L] = dotrow(w[0], g, 0.f);
                    }
                }
                if (p2act) {                   // wih2_i vs h1 window ph-3
                    const _Float16* hw = &h1ring[(par ^ 1) * 8][0];
                    float (*po)[4][HID] = p2buf[par ^ 1];
                    #pragma unroll
                    for (int j = 0; j < WD; ++j) {
                        const uint4v* hp = reinterpret_cast<const uint4v*>(hw + j * HID);
                        uint4v g[8];
                        #pragma unroll
                        for (int k = 0; k < 8; ++k) g[k] = hp[k];
                        po[j][0][L] = dotrow(w[1], g, 0.f);
                    }
                }
            } else {                           // wv == 7: wih2_{f,g,o}
                if (p2act) {
                    const _Float16* hw = &h1ring[(par ^ 1) * 8][0];
                    float (*po)[4][HID] = p2buf[par ^ 1];
                    #pragma unroll
                    for (int j = 0; j < WD; ++j) {
                        const uint4v* hp = reinterpret_cast<const uint4v*>(hw + j * HID);
                        uint4v g[8];
                        #pragma unroll
                        for (int k = 0; k < 8; ++k) g[k] = hp[k];
                        po[j][1][L] = dotrow(w[0], g, 0.f);
                        po[j][2][L] = dotrow(w[1], g, 0.f);
                        po[j][3][L] = dotrow(w[2], g, 0.f);
                    }
                }
            }
        }

        __syncthreads();   // publish window: h rings + p-buffers
    }

    // Final FC (f32): h2[2047] -> slot 2047&1 = 1.
    if (tid < EMB) {
        float acc = fcb[tid];
        const _Float16* hf = &h2ring[1][0];
        const float4* W4 = reinterpret_cast<const float4*>(fcW + tid * HID);
        #pragma unroll
        for (int k = 0; k < 16; ++k) {
            float4 wv4 = W4[k];
            acc = fmaf(wv4.x, (float)hf[4 * k + 0], acc);
            acc = fmaf(wv4.y, (float)hf[4 * k + 1], acc);
            acc = fmaf(wv4.z, (float)hf[4 * k + 2], acc);
            acc = fmaf(wv4.w, (float)hf[4 * k + 3], acc);
        }
        out[b * EMB + tid] = acc;
    }
}

extern "C" void kernel_launch(void* const* d_in, const int* in_sizes, int n_in,
                              void* d_out, int out_size, void* d_ws, size_t ws_size,
                              hipStream_t stream) {
    const float* x    = (const float*)d_in[0];
    const float* Wih0 = (const float*)d_in[1];
    const float* Whh0 = (const float*)d_in[2];
    const float* bih0 = (const float*)d_in[3];
    const float* bhh0 = (const float*)d_in[4];
    const float* Wih1 = (const float*)d_in[5];
    const float* Whh1 = (const float*)d_in[6];
    const float* bih1 = (const float*)d_in[7];
    const float* bhh1 = (const float*)d_in[8];
    const float* Wih2 = (const float*)d_in[9];
    const float* Whh2 = (const float*)d_in[10];
    const float* bih2 = (const float*)d_in[11];
    const float* bhh2 = (const float*)d_in[12];
    const float* fcW  = (const float*)d_in[13];
    const float* fcb  = (const float*)d_in[14];
    float* out = (float*)d_out;

    lstm3_fused<<<dim3(256), dim3(512), 0, stream>>>(
        x, Wih0, Whh0, bih0, bhh0,
        Wih1, Whh1, bih1, bhh1,
        Wih2, Whh2, bih2, bhh2,
        fcW, fcb, out);
}